// Round 8
// baseline (210.137 us; speedup 1.0000x reference)
//
#include <hip/hip_runtime.h>

// ---------------------------------------------------------------------------
// CustomAttention: cosine-sim MHA.  N=1024 seq, B=4 batch, C=1024, H=16, hd=64
// R8 = R7 with compile fix: cvt_pkrtz returns __fp16x2, union member uses that
//     type (bit-identical to _Float16x2; union only reinterprets to u32).
// R7: flash softmax VALU cut: (a) row-sum l via ones-MFMA instead of 24
//     v_add/kt + end shuffles; (b) P/xb packing via v_cvt_pkrtz.
// ---------------------------------------------------------------------------

typedef _Float16 f16x8 __attribute__((ext_vector_type(8)));
typedef __fp16   fp16x2 __attribute__((ext_vector_type(2)));
typedef float    f32x4 __attribute__((ext_vector_type(4)));

#define LOG2E 1.4426950408889634f
#define LOGMAX 4.6051702f   // log(100)

#define GLOAD16(g, l) \
    __builtin_amdgcn_global_load_lds((__attribute__((address_space(1))) void*)(g), \
                                     (__attribute__((address_space(3))) void*)(l), 16, 0, 0)

__device__ __forceinline__ unsigned short f2h(float x) {
    union { _Float16 h; unsigned short u; } cv;
    cv.h = (_Float16)x;
    return cv.u;
}

union h2u { fp16x2 h; unsigned int u; };

// ---- fp32 -> fp16 convert, all 5 tensors in one launch ----
__global__ __launch_bounds__(256) void cvt_all(
    const float* __restrict__ q, const float* __restrict__ k,
    const float* __restrict__ v, const float* __restrict__ w,
    const float* __restrict__ ow,
    unsigned short* __restrict__ qbf, unsigned short* __restrict__ kbf,
    unsigned short* __restrict__ vbf, unsigned short* __restrict__ wbf,
    unsigned short* __restrict__ owbf)
{
    int b = blockIdx.x;
    const float* src; unsigned short* dst; int idx;
    if      (b < 4096)  { src = q;  dst = qbf;  idx = b; }
    else if (b < 8192)  { src = k;  dst = kbf;  idx = b - 4096; }
    else if (b < 12288) { src = v;  dst = vbf;  idx = b - 8192; }
    else if (b < 15360) { src = w;  dst = wbf;  idx = b - 12288; }
    else                { src = ow; dst = owbf; idx = b - 15360; }
    int i = idx * 256 + threadIdx.x;
    float4 val = ((const float4*)src)[i];
    h2u p01, p23;
    p01.h = __builtin_amdgcn_cvt_pkrtz(val.x, val.y);
    p23.h = __builtin_amdgcn_cvt_pkrtz(val.z, val.w);
    ((uint2*)dst)[i] = (uint2){p01.u, p23.u};
}

// ---- projection GEMM + fused l2norm epilogue (unchanged from R5) ----
__global__ __launch_bounds__(256) void proj_gemm(
    const unsigned short* __restrict__ qbf, const unsigned short* __restrict__ kbf,
    const unsigned short* __restrict__ vbf, const unsigned short* __restrict__ wbf,
    const float* __restrict__ bias, const float* __restrict__ lsc,
    unsigned short* __restrict__ qn, unsigned short* __restrict__ kn,
    unsigned short* __restrict__ vT)
{
    __shared__ __align__(16) unsigned short AsmF[128 * 64];
    __shared__ __align__(16) unsigned short BsmF[128 * 64];
    int tid = threadIdx.x;
    int lane = tid & 63, wave = tid >> 6;
    int lr = lane & 15, lq = lane >> 4;
    int wr = wave >> 1, wc = wave & 1;

    int lin = blockIdx.x;
    int xcd = lin & 7, s = lin >> 3;
    int xt = s & 7, yy = (s >> 3) & 3, z = s >> 5;
    int m0 = (xcd * 4 + yy) * 128, n0 = xt * 128;

    const unsigned short* A = (z == 0) ? qbf : (z == 1) ? kbf : vbf;
    const unsigned short* W = wbf + (size_t)z * 1024 * 1024;

    int rl = lane >> 3;
    int cg = ((lane & 7) ^ rl) << 3;                     // halves
    const unsigned short* gA = A + (size_t)(m0 + wave * 32 + rl) * 1024 + cg;
    const unsigned short* gB = W + (size_t)(n0 + wave * 32 + rl) * 1024 + cg;
    unsigned short* lA = &AsmF[wave * 32 * 64];
    unsigned short* lB = &BsmF[wave * 32 * 64];

    int swz = lr & 7;
    int c0 = (lq ^ swz) << 3;
    int c1 = ((lq ^ 4) ^ swz) << 3;

    f32x4 acc[4][4];
    for (int i = 0; i < 4; i++) for (int j = 0; j < 4; j++) acc[i][j] = (f32x4){0.f, 0.f, 0.f, 0.f};

    for (int ki = 0; ki < 16; ++ki) {
        for (int j = 0; j < 4; ++j) {
            GLOAD16(gA + ki * 64 + j * 8192, lA + j * 512);
            GLOAD16(gB + ki * 64 + j * 8192, lB + j * 512);
        }
        __syncthreads();
        for (int kc = 0; kc < 2; ++kc) {
            int co = kc ? c1 : c0;
            f16x8 af[4], bfr[4];
            for (int mi = 0; mi < 4; ++mi) af[mi]  = *(const f16x8*)&AsmF[(wr * 64 + mi * 16 + lr) * 64 + co];
            for (int ni = 0; ni < 4; ++ni) bfr[ni] = *(const f16x8*)&BsmF[(wc * 64 + ni * 16 + lr) * 64 + co];
            for (int mi = 0; mi < 4; ++mi)
                for (int ni = 0; ni < 4; ++ni)
                    acc[mi][ni] = __builtin_amdgcn_mfma_f32_16x16x32_f16(af[mi], bfr[ni], acc[mi][ni], 0, 0, 0);
        }
        __syncthreads();
    }

    int h = (n0 >> 6) + wc;
    float bv[4];
    for (int ni = 0; ni < 4; ++ni) bv[ni] = bias[z * 1024 + n0 + wc * 64 + ni * 16 + lr];
    for (int mi = 0; mi < 4; ++mi)
        for (int ni = 0; ni < 4; ++ni)
            for (int r = 0; r < 4; ++r) acc[mi][ni][r] += bv[ni];

    float lsfac = __expf(fminf(lsc[h], LOGMAX)) * LOG2E;

    for (int mi = 0; mi < 4; ++mi)
        for (int r = 0; r < 4; ++r) {
            int row = m0 + wr * 64 + mi * 16 + lq * 4 + r;   // m = n*4 + b
            int n = row >> 2, b = row & 3;
            int bh = b * 16 + h;
            if (z < 2) {
                float ss = 0.f;
                for (int ni = 0; ni < 4; ++ni) ss += acc[mi][ni][r] * acc[mi][ni][r];
                for (int off = 1; off < 16; off <<= 1) ss += __shfl_xor(ss, off);
                float scale = 1.0f / fmaxf(sqrtf(ss), 1e-12f);
                if (z == 0) scale *= lsfac;
                unsigned short* dst = (z == 0) ? qn : kn;
                for (int ni = 0; ni < 4; ++ni)
                    dst[(size_t)bh * 65536 + (size_t)n * 64 + ni * 16 + lr] = f2h(acc[mi][ni][r] * scale);
            } else {
                for (int ni = 0; ni < 4; ++ni)
                    vT[(size_t)bh * 65536 + (size_t)(ni * 16 + lr) * 1024 + n] = f2h(acc[mi][ni][r]);
            }
        }
}

// ---- flash attention: 128 q-rows/block, 2 q-groups per wave ----
// grid 512; XCD swizzle: xcd owns 8 heads x 8 q-tiles, qt fastest.
// l computed via ones-MFMA; P packed with cvt_pkrtz; QK acc init = -off.
__global__ __launch_bounds__(256) void flash_kernel(
    const unsigned short* __restrict__ qn, const unsigned short* __restrict__ kn,
    const unsigned short* __restrict__ vT, const float* __restrict__ lsc,
    unsigned short* __restrict__ xb)
{
    __shared__ __align__(16) unsigned short K_flat[64 * 64];
    __shared__ __align__(16) unsigned short V_flat[64 * 64];     // [d][kpos]
    __shared__ __align__(16) unsigned short P_lds[4][2][16][72]; // [wave][grp][qrow][kpos]
    int tid = threadIdx.x;
    int lane = tid & 63, wave = tid >> 6;
    int lr = lane & 15, lq = lane >> 4;

    int lin = blockIdx.x;
    int xcd = lin & 7, s = lin >> 3;
    int qt = s & 7, bh = xcd * 8 + (s >> 3);
    int q0 = qt * 128;

    // static softmax offset folded into QK accumulator init
    float off = __expf(fminf(lsc[bh & 15], LOGMAX)) * LOG2E - 12.0f;
    f32x4 initv = (f32x4){-off, -off, -off, -off};

    f16x8 onev;
    for (int j = 0; j < 8; ++j) onev[j] = (_Float16)1.0f;

    f16x8 qf[2][2];   // [group][kc]  B-frag: Q[qrow][d]
    for (int g = 0; g < 2; ++g)
        for (int kc = 0; kc < 2; ++kc)
            qf[g][kc] = *(const f16x8*)(qn + (size_t)bh * 65536 +
                          (size_t)(q0 + g * 64 + wave * 16 + lr) * 64 + kc * 32 + lq * 8);

    int rl = lane >> 3;
    int cg = ((lane & 7) ^ rl) << 3;
    const unsigned short* gK = kn + (size_t)bh * 65536 + (size_t)(wave * 16 + rl) * 64 + cg;
    const unsigned short* gV = vT + (size_t)bh * 65536 + (size_t)(wave * 16 + rl) * 1024 + cg;
    unsigned short* lK = &K_flat[wave * 16 * 64];
    unsigned short* lV = &V_flat[wave * 16 * 64];
    int swz = lr & 7;
    int c0 = (lq ^ swz) << 3;
    int c1 = ((lq ^ 4) ^ swz) << 3;

    f32x4 o[2][4];    // [group][nt]  O^T[d][qrow]
    for (int g = 0; g < 2; ++g) for (int i = 0; i < 4; i++) o[g][i] = (f32x4){0.f, 0.f, 0.f, 0.f};
    f32x4 ol[2];      // l accumulator: C[m][n] = sum_k p[n][k] (same for all m)
    ol[0] = (f32x4){0.f, 0.f, 0.f, 0.f};
    ol[1] = (f32x4){0.f, 0.f, 0.f, 0.f};

    for (int kt = 0; kt < 16; ++kt) {
        for (int j = 0; j < 2; ++j) {
            GLOAD16(gK + kt * 4096 + j * 512,  lK + j * 512);
            GLOAD16(gV + kt * 64  + j * 8192,  lV + j * 512);
        }
        __syncthreads();

        // S^T = K Q^T - off : one K-frag read feeds both q-groups
        f32x4 sc[2][4];
        for (int ct = 0; ct < 4; ++ct) {
            for (int kc = 0; kc < 2; ++kc) {
                f16x8 kf = *(const f16x8*)&K_flat[(ct * 16 + lr) * 64 + (kc ? c1 : c0)];
                for (int g = 0; g < 2; ++g)
                    sc[g][ct] = __builtin_amdgcn_mfma_f32_16x16x32_f16(
                        kf, qf[g][kc], kc == 0 ? initv : sc[g][ct], 0, 0, 0);
            }
        }

        // p = exp2(sc); pack 4 -> uint2 (2x cvt_pkrtz) -> b64 LDS write
        for (int g = 0; g < 2; ++g)
            for (int ct = 0; ct < 4; ++ct) {
                float p0 = exp2f(sc[g][ct][0]), p1 = exp2f(sc[g][ct][1]);
                float p2 = exp2f(sc[g][ct][2]), p3 = exp2f(sc[g][ct][3]);
                h2u a01, a23;
                a01.h = __builtin_amdgcn_cvt_pkrtz(p0, p1);
                a23.h = __builtin_amdgcn_cvt_pkrtz(p2, p3);
                *(uint2*)&P_lds[wave][g][lr][ct * 16 + lq * 4] = (uint2){a01.u, a23.u};
            }

        // O^T += V^T @ P^T ; l += ones @ P^T
        f16x8 pf[2][2];
        for (int g = 0; g < 2; ++g)
            for (int kc = 0; kc < 2; ++kc)
                pf[g][kc] = *(const f16x8*)&P_lds[wave][g][lr][kc * 32 + lq * 8];
        for (int g = 0; g < 2; ++g)
            for (int kc = 0; kc < 2; ++kc)
                ol[g] = __builtin_amdgcn_mfma_f32_16x16x32_f16(onev, pf[g][kc], ol[g], 0, 0, 0);
        for (int nt = 0; nt < 4; ++nt)
            for (int kc = 0; kc < 2; ++kc) {
                f16x8 vf = *(const f16x8*)&V_flat[(nt * 16 + lr) * 64 + (kc ? c1 : c0)];
                for (int g = 0; g < 2; ++g)
                    o[g][nt] = __builtin_amdgcn_mfma_f32_16x16x32_f16(vf, pf[g][kc], o[g][nt], 0, 0, 0);
            }
        __syncthreads();
    }

    int b = bh >> 4, h = bh & 15;
    for (int g = 0; g < 2; ++g) {
        float inv = 1.0f / ol[g][0];      // all regs hold l(qrow=lr)
        size_t m = (size_t)(q0 + g * 64 + wave * 16 + lr) * 4 + b;
        h2u w01, w23;
        for (int nt = 0; nt < 4; ++nt) {
            w01.h = __builtin_amdgcn_cvt_pkrtz(o[g][nt][0] * inv, o[g][nt][1] * inv);
            w23.h = __builtin_amdgcn_cvt_pkrtz(o[g][nt][2] * inv, o[g][nt][3] * inv);
            *(uint2*)(xb + m * 1024 + h * 64 + nt * 16 + lq * 4) = (uint2){w01.u, w23.u};
        }
    }
}

// ---- output GEMM: out(4096x1024) = X @ out_w^T + out_b;  128x64 tiles ----
__global__ __launch_bounds__(256) void out_gemm(
    const unsigned short* __restrict__ xb, const unsigned short* __restrict__ owbf,
    const float* __restrict__ bias, float* __restrict__ outp)
{
    __shared__ __align__(16) unsigned short AsmF[128 * 64];
    __shared__ __align__(16) unsigned short BsmF[64 * 64];
    int tid = threadIdx.x;
    int lane = tid & 63, wave = tid >> 6;
    int lr = lane & 15, lq = lane >> 4;

    int lin = blockIdx.x;
    int xcd = lin & 7, s = lin >> 3;
    int xt = s & 15, yy = s >> 4;
    int m0 = (xcd * 4 + yy) * 128, n0 = xt * 64;

    int rl = lane >> 3;
    int cg = ((lane & 7) ^ rl) << 3;
    const unsigned short* gA = xb   + (size_t)(m0 + wave * 32 + rl) * 1024 + cg;
    const unsigned short* gB = owbf + (size_t)(n0 + wave * 16 + rl) * 1024 + cg;
    unsigned short* lA = &AsmF[wave * 32 * 64];
    unsigned short* lB = &BsmF[wave * 16 * 64];
    int swz = lr & 7;
    int c0 = (lq ^ swz) << 3;
    int c1 = ((lq ^ 4) ^ swz) << 3;

    f32x4 acc[2][4];
    for (int i = 0; i < 2; i++) for (int j = 0; j < 4; j++) acc[i][j] = (f32x4){0.f, 0.f, 0.f, 0.f};

    for (int ki = 0; ki < 16; ++ki) {
        for (int j = 0; j < 4; ++j)
            GLOAD16(gA + ki * 64 + j * 8192, lA + j * 512);
        for (int j = 0; j < 2; ++j)
            GLOAD16(gB + ki * 64 + j * 8192, lB + j * 512);
        __syncthreads();
        for (int kc = 0; kc < 2; ++kc) {
            int co = kc ? c1 : c0;
            f16x8 af[2], bfr[4];
            for (int mi = 0; mi < 2; ++mi) af[mi]  = *(const f16x8*)&AsmF[(wave * 32 + mi * 16 + lr) * 64 + co];
            for (int ni = 0; ni < 4; ++ni) bfr[ni] = *(const f16x8*)&BsmF[(ni * 16 + lr) * 64 + co];
            for (int mi = 0; mi < 2; ++mi)
                for (int ni = 0; ni < 4; ++ni)
                    acc[mi][ni] = __builtin_amdgcn_mfma_f32_16x16x32_f16(af[mi], bfr[ni], acc[mi][ni], 0, 0, 0);
        }
        __syncthreads();
    }
    for (int mi = 0; mi < 2; ++mi)
        for (int ni = 0; ni < 4; ++ni)
            for (int r = 0; r < 4; ++r) {
                int row = m0 + wave * 32 + mi * 16 + lq * 4 + r;
                int col = n0 + ni * 16 + lr;
                outp[(size_t)row * 1024 + col] = acc[mi][ni][r] + bias[col];
            }
}

extern "C" void kernel_launch(void* const* d_in, const int* in_sizes, int n_in,
                              void* d_out, int out_size, void* d_ws, size_t ws_size,
                              hipStream_t stream) {
    const float* query = (const float*)d_in[0];
    const float* key   = (const float*)d_in[1];
    const float* value = (const float*)d_in[2];
    const float* ipw   = (const float*)d_in[3];
    const float* ipb   = (const float*)d_in[4];
    const float* lsc   = (const float*)d_in[5];
    const float* ow    = (const float*)d_in[6];
    const float* ob    = (const float*)d_in[7];
    float* outp = (float*)d_out;

    char* ws = (char*)d_ws;
    unsigned short* qbf  = (unsigned short*)(ws);               // 8 MB fp16 query
    unsigned short* kbf  = (unsigned short*)(ws + 8388608);     // 8 MB
    unsigned short* vbf  = (unsigned short*)(ws + 16777216);    // 8 MB
    unsigned short* wbf  = (unsigned short*)(ws + 25165824);    // 6 MB in_proj_w
    unsigned short* owbf = (unsigned short*)(ws + 31457280);    // 2 MB out_w
    unsigned short* qn   = (unsigned short*)(ws + 33554432);    // 8 MB normalized q (bh,n,d)
    unsigned short* kn   = (unsigned short*)(ws + 41943040);    // 8 MB normalized k
    unsigned short* vT   = (unsigned short*)(ws + 50331648);    // 8 MB v^T (bh,d,n)
    unsigned short* xbuf = (unsigned short*)(ws + 58720256);    // 8 MB attn out (m, c) row-major

    cvt_all<<<16384, 256, 0, stream>>>(query, key, value, ipw, ow,
                                       qbf, kbf, vbf, wbf, owbf);
    proj_gemm<<<768, 256, 0, stream>>>(qbf, kbf, vbf, wbf, ipb, lsc, qn, kn, vT);
    flash_kernel<<<512, 256, 0, stream>>>(qn, kn, vT, lsc, xbuf);
    out_gemm<<<512, 256, 0, stream>>>(xbuf, owbf, ob, outp);
}

// Round 10
// 209.735 us; speedup vs baseline: 1.0019x; 1.0019x over previous
//
#include <hip/hip_runtime.h>

// ---------------------------------------------------------------------------
// CustomAttention: cosine-sim MHA.  N=1024 seq, B=4 batch, C=1024, H=16, hd=64
// R10 = R9 with builtin-name fix: legacy K=16 MFMA is ...16x16x16f16 (no
//     underscore), unlike the gfx950-new ...16x16x32_f16.
// R9: flash serial-chain cut: (a) PV via 16x16x16 MFMA whose B-operand layout
//     (k=lq*4+j) matches the QK C/D layout (row=lq*4+r) -> P stays in
//     registers, P_lds round-trip deleted; (b) K/V double-buffered, ONE
//     barrier per kt, loads(kt+1) issued before compute(kt).
// ---------------------------------------------------------------------------

typedef _Float16 f16x8 __attribute__((ext_vector_type(8)));
typedef _Float16 f16x4 __attribute__((ext_vector_type(4)));
typedef __fp16   fp16x2 __attribute__((ext_vector_type(2)));
typedef float    f32x4 __attribute__((ext_vector_type(4)));

#define LOG2E 1.4426950408889634f
#define LOGMAX 4.6051702f   // log(100)

#define GLOAD16(g, l) \
    __builtin_amdgcn_global_load_lds((__attribute__((address_space(1))) void*)(g), \
                                     (__attribute__((address_space(3))) void*)(l), 16, 0, 0)

__device__ __forceinline__ unsigned short f2h(float x) {
    union { _Float16 h; unsigned short u; } cv;
    cv.h = (_Float16)x;
    return cv.u;
}

union h2u { fp16x2 h; unsigned int u; };
union u2h4 { uint2 u; f16x4 h; };

// ---- fp32 -> fp16 convert, all 5 tensors in one launch ----
__global__ __launch_bounds__(256) void cvt_all(
    const float* __restrict__ q, const float* __restrict__ k,
    const float* __restrict__ v, const float* __restrict__ w,
    const float* __restrict__ ow,
    unsigned short* __restrict__ qbf, unsigned short* __restrict__ kbf,
    unsigned short* __restrict__ vbf, unsigned short* __restrict__ wbf,
    unsigned short* __restrict__ owbf)
{
    int b = blockIdx.x;
    const float* src; unsigned short* dst; int idx;
    if      (b < 4096)  { src = q;  dst = qbf;  idx = b; }
    else if (b < 8192)  { src = k;  dst = kbf;  idx = b - 4096; }
    else if (b < 12288) { src = v;  dst = vbf;  idx = b - 8192; }
    else if (b < 15360) { src = w;  dst = wbf;  idx = b - 12288; }
    else                { src = ow; dst = owbf; idx = b - 15360; }
    int i = idx * 256 + threadIdx.x;
    float4 val = ((const float4*)src)[i];
    h2u p01, p23;
    p01.h = __builtin_amdgcn_cvt_pkrtz(val.x, val.y);
    p23.h = __builtin_amdgcn_cvt_pkrtz(val.z, val.w);
    ((uint2*)dst)[i] = (uint2){p01.u, p23.u};
}

// ---- projection GEMM + fused l2norm epilogue (unchanged from R5) ----
__global__ __launch_bounds__(256) void proj_gemm(
    const unsigned short* __restrict__ qbf, const unsigned short* __restrict__ kbf,
    const unsigned short* __restrict__ vbf, const unsigned short* __restrict__ wbf,
    const float* __restrict__ bias, const float* __restrict__ lsc,
    unsigned short* __restrict__ qn, unsigned short* __restrict__ kn,
    unsigned short* __restrict__ vT)
{
    __shared__ __align__(16) unsigned short AsmF[128 * 64];
    __shared__ __align__(16) unsigned short BsmF[128 * 64];
    int tid = threadIdx.x;
    int lane = tid & 63, wave = tid >> 6;
    int lr = lane & 15, lq = lane >> 4;
    int wr = wave >> 1, wc = wave & 1;

    int lin = blockIdx.x;
    int xcd = lin & 7, s = lin >> 3;
    int xt = s & 7, yy = (s >> 3) & 3, z = s >> 5;
    int m0 = (xcd * 4 + yy) * 128, n0 = xt * 128;

    const unsigned short* A = (z == 0) ? qbf : (z == 1) ? kbf : vbf;
    const unsigned short* W = wbf + (size_t)z * 1024 * 1024;

    int rl = lane >> 3;
    int cg = ((lane & 7) ^ rl) << 3;                     // halves
    const unsigned short* gA = A + (size_t)(m0 + wave * 32 + rl) * 1024 + cg;
    const unsigned short* gB = W + (size_t)(n0 + wave * 32 + rl) * 1024 + cg;
    unsigned short* lA = &AsmF[wave * 32 * 64];
    unsigned short* lB = &BsmF[wave * 32 * 64];

    int swz = lr & 7;
    int c0 = (lq ^ swz) << 3;
    int c1 = ((lq ^ 4) ^ swz) << 3;

    f32x4 acc[4][4];
    for (int i = 0; i < 4; i++) for (int j = 0; j < 4; j++) acc[i][j] = (f32x4){0.f, 0.f, 0.f, 0.f};

    for (int ki = 0; ki < 16; ++ki) {
        for (int j = 0; j < 4; ++j) {
            GLOAD16(gA + ki * 64 + j * 8192, lA + j * 512);
            GLOAD16(gB + ki * 64 + j * 8192, lB + j * 512);
        }
        __syncthreads();
        for (int kc = 0; kc < 2; ++kc) {
            int co = kc ? c1 : c0;
            f16x8 af[4], bfr[4];
            for (int mi = 0; mi < 4; ++mi) af[mi]  = *(const f16x8*)&AsmF[(wr * 64 + mi * 16 + lr) * 64 + co];
            for (int ni = 0; ni < 4; ++ni) bfr[ni] = *(const f16x8*)&BsmF[(wc * 64 + ni * 16 + lr) * 64 + co];
            for (int mi = 0; mi < 4; ++mi)
                for (int ni = 0; ni < 4; ++ni)
                    acc[mi][ni] = __builtin_amdgcn_mfma_f32_16x16x32_f16(af[mi], bfr[ni], acc[mi][ni], 0, 0, 0);
        }
        __syncthreads();
    }

    int h = (n0 >> 6) + wc;
    float bv[4];
    for (int ni = 0; ni < 4; ++ni) bv[ni] = bias[z * 1024 + n0 + wc * 64 + ni * 16 + lr];
    for (int mi = 0; mi < 4; ++mi)
        for (int ni = 0; ni < 4; ++ni)
            for (int r = 0; r < 4; ++r) acc[mi][ni][r] += bv[ni];

    float lsfac = __expf(fminf(lsc[h], LOGMAX)) * LOG2E;

    for (int mi = 0; mi < 4; ++mi)
        for (int r = 0; r < 4; ++r) {
            int row = m0 + wr * 64 + mi * 16 + lq * 4 + r;   // m = n*4 + b
            int n = row >> 2, b = row & 3;
            int bh = b * 16 + h;
            if (z < 2) {
                float ss = 0.f;
                for (int ni = 0; ni < 4; ++ni) ss += acc[mi][ni][r] * acc[mi][ni][r];
                for (int off = 1; off < 16; off <<= 1) ss += __shfl_xor(ss, off);
                float scale = 1.0f / fmaxf(sqrtf(ss), 1e-12f);
                if (z == 0) scale *= lsfac;
                unsigned short* dst = (z == 0) ? qn : kn;
                for (int ni = 0; ni < 4; ++ni)
                    dst[(size_t)bh * 65536 + (size_t)n * 64 + ni * 16 + lr] = f2h(acc[mi][ni][r] * scale);
            } else {
                for (int ni = 0; ni < 4; ++ni)
                    vT[(size_t)bh * 65536 + (size_t)(ni * 16 + lr) * 1024 + n] = f2h(acc[mi][ni][r]);
            }
        }
}

// ---- flash attention: 128 q-rows/block, 2 q-groups/wave, dbuf K/V,
//      register-resident P via 16x16x16 PV MFMAs ----
__global__ __launch_bounds__(256) void flash_kernel(
    const unsigned short* __restrict__ qn, const unsigned short* __restrict__ kn,
    const unsigned short* __restrict__ vT, const float* __restrict__ lsc,
    unsigned short* __restrict__ xb)
{
    __shared__ __align__(16) unsigned short K_flat[2][64 * 64];
    __shared__ __align__(16) unsigned short V_flat[2][64 * 64];  // [d][kpos]
    int tid = threadIdx.x;
    int lane = tid & 63, wave = tid >> 6;
    int lr = lane & 15, lq = lane >> 4;

    int lin = blockIdx.x;
    int xcd = lin & 7, s = lin >> 3;
    int qt = s & 7, bh = xcd * 8 + (s >> 3);
    int q0 = qt * 128;

    // static softmax offset folded into QK accumulator init
    float off = __expf(fminf(lsc[bh & 15], LOGMAX)) * LOG2E - 12.0f;
    f32x4 initv = (f32x4){-off, -off, -off, -off};

    f16x4 onev4;
    for (int j = 0; j < 4; ++j) onev4[j] = (_Float16)1.0f;

    f16x8 qf[2][2];   // [group][kc]  B-frag: Q[qrow][d]
    for (int g = 0; g < 2; ++g)
        for (int kc = 0; kc < 2; ++kc)
            qf[g][kc] = *(const f16x8*)(qn + (size_t)bh * 65536 +
                          (size_t)(q0 + g * 64 + wave * 16 + lr) * 64 + kc * 32 + lq * 8);

    int rl = lane >> 3;
    int cg = ((lane & 7) ^ rl) << 3;
    const unsigned short* gK = kn + (size_t)bh * 65536 + (size_t)(wave * 16 + rl) * 64 + cg;
    const unsigned short* gV = vT + (size_t)bh * 65536 + (size_t)(wave * 16 + rl) * 1024 + cg;
    int swz = lr & 7;
    int c0 = (lq ^ swz) << 3;
    int c1 = ((lq ^ 4) ^ swz) << 3;

    f32x4 o[2][4];    // [group][nt]  O^T[d][qrow]
    for (int g = 0; g < 2; ++g) for (int i = 0; i < 4; i++) o[g][i] = (f32x4){0.f, 0.f, 0.f, 0.f};
    f32x4 ol[2];      // l accumulator
    ol[0] = (f32x4){0.f, 0.f, 0.f, 0.f};
    ol[1] = (f32x4){0.f, 0.f, 0.f, 0.f};

    // prologue: stage kt=0 into buffer 0
    for (int j = 0; j < 2; ++j) {
        GLOAD16(gK + j * 512,  &K_flat[0][wave * 16 * 64] + j * 512);
        GLOAD16(gV + j * 8192, &V_flat[0][wave * 16 * 64] + j * 512);
    }

    for (int kt = 0; kt < 16; ++kt) {
        __syncthreads();   // drains loads(kt); all waves done reading buf[(kt+1)&1]

        if (kt < 15) {
            int nb = (kt + 1) & 1;
            for (int j = 0; j < 2; ++j) {
                GLOAD16(gK + (kt + 1) * 4096 + j * 512,  &K_flat[nb][wave * 16 * 64] + j * 512);
                GLOAD16(gV + (kt + 1) * 64  + j * 8192,  &V_flat[nb][wave * 16 * 64] + j * 512);
            }
        }
        const unsigned short* Kb = K_flat[kt & 1];
        const unsigned short* Vb = V_flat[kt & 1];

        // S^T = K Q^T - off : one K-frag read feeds both q-groups
        f32x4 sc[2][4];
        for (int ct = 0; ct < 4; ++ct) {
            for (int kc = 0; kc < 2; ++kc) {
                f16x8 kf = *(const f16x8*)&Kb[(ct * 16 + lr) * 64 + (kc ? c1 : c0)];
                for (int g = 0; g < 2; ++g)
                    sc[g][ct] = __builtin_amdgcn_mfma_f32_16x16x32_f16(
                        kf, qf[g][kc], kc == 0 ? initv : sc[g][ct], 0, 0, 0);
            }
        }

        // p = exp2(sc), packed in-register: C-layout (row=lq*4+r) ==
        // 16x16x16 B-layout (k=lq*4+j) -> no LDS round-trip
        f16x4 ph[2][4];
        for (int g = 0; g < 2; ++g)
            for (int ct = 0; ct < 4; ++ct) {
                float p0 = exp2f(sc[g][ct][0]), p1 = exp2f(sc[g][ct][1]);
                float p2 = exp2f(sc[g][ct][2]), p3 = exp2f(sc[g][ct][3]);
                h2u a01, a23;
                a01.h = __builtin_amdgcn_cvt_pkrtz(p0, p1);
                a23.h = __builtin_amdgcn_cvt_pkrtz(p2, p3);
                u2h4 pb; pb.u = (uint2){a01.u, a23.u};
                ph[g][ct] = pb.h;
            }

        // l += ones @ P^T   (16x16x16)
        for (int g = 0; g < 2; ++g)
            for (int ct = 0; ct < 4; ++ct)
                ol[g] = __builtin_amdgcn_mfma_f32_16x16x16f16(onev4, ph[g][ct], ol[g], 0, 0, 0);

        // O^T += V^T @ P^T  (16x16x16); V A-frag: A[m=d][k=lq*4+j] per ct
        for (int nt = 0; nt < 4; ++nt)
            for (int ct = 0; ct < 4; ++ct) {
                int vc = (((2 * ct + (lq >> 1)) ^ swz) << 3) + ((lq & 1) << 2);
                f16x4 vf = *(const f16x4*)&Vb[(nt * 16 + lr) * 64 + vc];
                for (int g = 0; g < 2; ++g)
                    o[g][nt] = __builtin_amdgcn_mfma_f32_16x16x16f16(vf, ph[g][ct], o[g][nt], 0, 0, 0);
            }
    }

    int b = bh >> 4, h = bh & 15;
    for (int g = 0; g < 2; ++g) {
        float inv = 1.0f / ol[g][0];      // all regs hold l(qrow=lr)
        size_t m = (size_t)(q0 + g * 64 + wave * 16 + lr) * 4 + b;
        h2u w01, w23;
        for (int nt = 0; nt < 4; ++nt) {
            w01.h = __builtin_amdgcn_cvt_pkrtz(o[g][nt][0] * inv, o[g][nt][1] * inv);
            w23.h = __builtin_amdgcn_cvt_pkrtz(o[g][nt][2] * inv, o[g][nt][3] * inv);
            *(uint2*)(xb + m * 1024 + h * 64 + nt * 16 + lq * 4) = (uint2){w01.u, w23.u};
        }
    }
}

// ---- output GEMM: out(4096x1024) = X @ out_w^T + out_b;  128x64 tiles ----
__global__ __launch_bounds__(256) void out_gemm(
    const unsigned short* __restrict__ xb, const unsigned short* __restrict__ owbf,
    const float* __restrict__ bias, float* __restrict__ outp)
{
    __shared__ __align__(16) unsigned short AsmF[128 * 64];
    __shared__ __align__(16) unsigned short BsmF[64 * 64];
    int tid = threadIdx.x;
    int lane = tid & 63, wave = tid >> 6;
    int lr = lane & 15, lq = lane >> 4;

    int lin = blockIdx.x;
    int xcd = lin & 7, s = lin >> 3;
    int xt = s & 15, yy = s >> 4;
    int m0 = (xcd * 4 + yy) * 128, n0 = xt * 64;

    int rl = lane >> 3;
    int cg = ((lane & 7) ^ rl) << 3;
    const unsigned short* gA = xb   + (size_t)(m0 + wave * 32 + rl) * 1024 + cg;
    const unsigned short* gB = owbf + (size_t)(n0 + wave * 16 + rl) * 1024 + cg;
    unsigned short* lA = &AsmF[wave * 32 * 64];
    unsigned short* lB = &BsmF[wave * 16 * 64];
    int swz = lr & 7;
    int c0 = (lq ^ swz) << 3;
    int c1 = ((lq ^ 4) ^ swz) << 3;

    f32x4 acc[2][4];
    for (int i = 0; i < 2; i++) for (int j = 0; j < 4; j++) acc[i][j] = (f32x4){0.f, 0.f, 0.f, 0.f};

    for (int ki = 0; ki < 16; ++ki) {
        for (int j = 0; j < 4; ++j)
            GLOAD16(gA + ki * 64 + j * 8192, lA + j * 512);
        for (int j = 0; j < 2; ++j)
            GLOAD16(gB + ki * 64 + j * 8192, lB + j * 512);
        __syncthreads();
        for (int kc = 0; kc < 2; ++kc) {
            int co = kc ? c1 : c0;
            f16x8 af[2], bfr[4];
            for (int mi = 0; mi < 2; ++mi) af[mi]  = *(const f16x8*)&AsmF[(wave * 32 + mi * 16 + lr) * 64 + co];
            for (int ni = 0; ni < 4; ++ni) bfr[ni] = *(const f16x8*)&BsmF[(ni * 16 + lr) * 64 + co];
            for (int mi = 0; mi < 2; ++mi)
                for (int ni = 0; ni < 4; ++ni)
                    acc[mi][ni] = __builtin_amdgcn_mfma_f32_16x16x32_f16(af[mi], bfr[ni], acc[mi][ni], 0, 0, 0);
        }
        __syncthreads();
    }
    for (int mi = 0; mi < 2; ++mi)
        for (int ni = 0; ni < 4; ++ni)
            for (int r = 0; r < 4; ++r) {
                int row = m0 + wave * 32 + mi * 16 + lq * 4 + r;
                int col = n0 + ni * 16 + lr;
                outp[(size_t)row * 1024 + col] = acc[mi][ni][r] + bias[col];
            }
}

extern "C" void kernel_launch(void* const* d_in, const int* in_sizes, int n_in,
                              void* d_out, int out_size, void* d_ws, size_t ws_size,
                              hipStream_t stream) {
    const float* query = (const float*)d_in[0];
    const float* key   = (const float*)d_in[1];
    const float* value = (const float*)d_in[2];
    const float* ipw   = (const float*)d_in[3];
    const float* ipb   = (const float*)d_in[4];
    const float* lsc   = (const float*)d_in[5];
    const float* ow    = (const float*)d_in[6];
    const float* ob    = (const float*)d_in[7];
    float* outp = (float*)d_out;

    char* ws = (char*)d_ws;
    unsigned short* qbf  = (unsigned short*)(ws);               // 8 MB fp16 query
    unsigned short* kbf  = (unsigned short*)(ws + 8388608);     // 8 MB
    unsigned short* vbf  = (unsigned short*)(ws + 16777216);    // 8 MB
    unsigned short* wbf  = (unsigned short*)(ws + 25165824);    // 6 MB in_proj_w
    unsigned short* owbf = (unsigned short*)(ws + 31457280);    // 2 MB out_w
    unsigned short* qn   = (unsigned short*)(ws + 33554432);    // 8 MB normalized q (bh,n,d)
    unsigned short* kn   = (unsigned short*)(ws + 41943040);    // 8 MB normalized k
    unsigned short* vT   = (unsigned short*)(ws + 50331648);    // 8 MB v^T (bh,d,n)
    unsigned short* xbuf = (unsigned short*)(ws + 58720256);    // 8 MB attn out (m, c) row-major

    cvt_all<<<16384, 256, 0, stream>>>(query, key, value, ipw, ow,
                                       qbf, kbf, vbf, wbf, owbf);
    proj_gemm<<<768, 256, 0, stream>>>(qbf, kbf, vbf, wbf, ipb, lsc, qn, kn, vT);
    flash_kernel<<<512, 256, 0, stream>>>(qn, kn, vT, lsc, xbuf);
    out_gemm<<<512, 256, 0, stream>>>(xbuf, owbf, ob, outp);
}